// Round 1
// baseline (86.467 us; speedup 1.0000x reference)
//
#include <hip/hip_runtime.h>
#include <math.h>

#define N_ 2048
#define K_ 512
#define J_ 256
#define BK 128            // K chunk (double-buffered)
#define NR 64             // n rows per block (row per lane)
#define NPAIR 32          // NR/2 row-pairs staged per 1024B global_load_lds
#define PP 260            // floats per row-pair: 2*BK + 4 (16B-aligned, banks spread to 8-access floor)

typedef __attribute__((address_space(3))) float       lds_f;
typedef const __attribute__((address_space(1))) float glb_f;

// Force 3-input max/min: 2 muls + 1 max3 + 1 min3 per 2 products = 2.0 VALU ops/product.
#define MAX3(acc, a, b) asm("v_max3_f32 %0, %0, %1, %2" : "+v"(acc) : "v"(a), "v"(b))
#define MIN3(acc, a, b) asm("v_min3_f32 %0, %0, %1, %2" : "+v"(acc) : "v"(a), "v"(b))

// Grid 512 blocks (2/CU) x 256 threads (8 waves/CU, 2/SIMD).
// Block tile: 64 n x 16 j. Wave w: 64 n (one per lane) x 4 j (wave-uniform -> w via
// scalar/broadcast loads, zero LDS traffic for w). x staged in LDS, double-buffered,
// read row-per-lane: one ds_read_b128 feeds 1024 products (0.5 B/product).
__global__ __launch_bounds__(256) void mam_fused2(
    const float* __restrict__ x, const float* __restrict__ w,
    const float* __restrict__ bias, float* __restrict__ out)
{
    __shared__ __align__(16) float xs[2][NPAIR * PP];   // 66,560 B -> 2 blocks/CU

    const int t    = threadIdx.x;
    const int lane = t & 63;
    const int wid  = __builtin_amdgcn_readfirstlane(t >> 6);   // force SGPR: makes w addrs uniform

    // XCD-chunked swizzle (bijective: 512 = 8 * 64): each XCD gets 4 n-groups x all j
    // -> per-XCD read set ~1MB (x tiles + w), L2-resident.
    const int wg0 = (int)blockIdx.x;
    const int wg  = (wg0 & 7) * 64 + (wg0 >> 3);
    const int bx  = wg & 15;            // j-block 0..15
    const int by  = wg >> 4;            // n-block 0..31

    const int n0  = by * NR;
    const int j0w = bx * 16 + wid * 4;  // this wave's 4 output columns (uniform)

    // Staging decomposition: one global_load_lds(16B) moves 1024B = one row-PAIR.
    // Lanes 0..31 -> even row bytes 0..511, lanes 32..63 -> odd row.
    const int sub = lane >> 5;           // row within pair
    const int kl  = (lane & 31) * 4;     // float offset within row

    // Compute-side read base: row = lane. Pair p at p*PP; odd row at +BK floats.
    const int xoff = (lane >> 1) * PP + (lane & 1) * BK;

    float mx[4], mn[4];
#pragma unroll
    for (int j = 0; j < 4; ++j) { mx[j] = -__builtin_inff(); mn[j] = __builtin_inff(); }

#define STAGE(buf, kc)                                                            \
    {                                                                             \
        _Pragma("unroll")                                                         \
        for (int p = 0; p < 8; ++p) {                                             \
            const int pair = wid * 8 + p;                                         \
            __builtin_amdgcn_global_load_lds(                                     \
                (glb_f*)(x + (size_t)(n0 + pair * 2 + sub) * K_ + (kc) + kl),     \
                (lds_f*)(&xs[buf][pair * PP]), 16, 0, 0);                         \
        }                                                                         \
    }

#define CHUNK(buf, kc)                                                            \
    {                                                                             \
        const float* xr = &xs[buf][xoff];                                         \
        const float* wr = w + (size_t)j0w * K_ + (kc);                            \
        _Pragma("unroll 8")                                                       \
        for (int kk = 0; kk < BK; kk += 4) {                                      \
            const float4 xv = *(const float4*)(xr + kk);                          \
            _Pragma("unroll")                                                     \
            for (int j = 0; j < 4; ++j) {                                         \
                const float4 wv = *(const float4*)(wr + (size_t)j * K_ + kk);     \
                const float p0 = xv.x * wv.x, p1 = xv.y * wv.y;                   \
                const float p2 = xv.z * wv.z, p3 = xv.w * wv.w;                   \
                MAX3(mx[j], p0, p1); MAX3(mx[j], p2, p3);                         \
                MIN3(mn[j], p0, p1); MIN3(mn[j], p2, p3);                         \
            }                                                                     \
        }                                                                         \
    }

    // Double-buffered pipeline over K = 4 chunks of 128.
    // Stage(c+1) issued BEFORE compute(c); __syncthreads drains vmcnt(0) after the
    // compute, so staging latency hides under ~2048 VALU cycles.
    STAGE(0, 0);
    __syncthreads();
    STAGE(1, BK);        CHUNK(0, 0);
    __syncthreads();
    STAGE(0, 2 * BK);    CHUNK(1, BK);
    __syncthreads();
    STAGE(1, 3 * BK);    CHUNK(0, 2 * BK);
    __syncthreads();
                         CHUNK(1, 3 * BK);

    const float4 bi = *(const float4*)&bias[j0w];
    float4 o;
    o.x = mx[0] + mn[0] + bi.x;
    o.y = mx[1] + mn[1] + bi.y;
    o.z = mx[2] + mn[2] + bi.z;
    o.w = mx[3] + mn[3] + bi.w;
    *(float4*)&out[(size_t)(n0 + lane) * J_ + j0w] = o;

#undef STAGE
#undef CHUNK
}

extern "C" void kernel_launch(void* const* d_in, const int* in_sizes, int n_in,
                              void* d_out, int out_size, void* d_ws, size_t ws_size,
                              hipStream_t stream) {
    const float* x    = (const float*)d_in[0];
    const float* w    = (const float*)d_in[1];
    const float* bias = (const float*)d_in[2];
    float* out = (float*)d_out;

    dim3 grid(512);   // 32 n-blocks x 16 j-blocks, XCD-swizzled in-kernel
    mam_fused2<<<grid, 256, 0, stream>>>(x, w, bias, out);
}

// Round 2
// 77.401 us; speedup vs baseline: 1.1171x; 1.1171x over previous
//
#include <hip/hip_runtime.h>
#include <math.h>

#define N_ 2048
#define K_ 512
#define J_ 256
#define BK 128            // K chunk (double-buffered)
#define NPAIR 32          // 64 rows staged as 32 row-pairs (1024B per global_load_lds)
#define PP 260            // floats per row-pair: 2*BK + 4 pad (16B-aligned, b128 reads at 8-way bank floor)

typedef __attribute__((address_space(3))) float       lds_f;
typedef const __attribute__((address_space(1))) float glb_f;
typedef float f32x16 __attribute__((ext_vector_type(16)));

// 2 muls + 1 max3 + 1 min3 per 2 products = 2.0 VALU ops/product.
#define MAX3(acc, a, b) asm("v_max3_f32 %0, %0, %1, %2" : "+v"(acc) : "v"(a), "v"(b))
#define MIN3(acc, a, b) asm("v_min3_f32 %0, %0, %1, %2" : "+v"(acc) : "v"(a), "v"(b))

// Grid 512 blocks (2/CU, 8 waves/CU, 2/SIMD) x 256 threads.
// Block tile: 64 n x 16 j. Wave: 64 n (one row per lane) x 4 j.
// x: LDS row-per-lane (1 ds_read_b128 per lane-quad = 1 B/product, 8-way = b128 floor).
// w: SCALAR PIPE — explicit s_load_dwordx16 into SGPRs (wave-uniform j rows).
//    Zero VALU / LDS / vector-VMEM cost; v_mul takes the SGPR operand directly.
__global__ __launch_bounds__(256) void mam_fused3(
    const float* __restrict__ x, const float* __restrict__ w,
    const float* __restrict__ bias, float* __restrict__ out)
{
    __shared__ __align__(16) float xs[2][NPAIR * PP];   // 66,560 B -> 2 blocks/CU

    const int t    = threadIdx.x;
    const int lane = t & 63;
    const int wid  = __builtin_amdgcn_readfirstlane(t >> 6);   // SGPR wave id

    // XCD-chunked bijective swizzle (512 = 8 * 64): each XCD sees 4 n-groups x all j
    // -> ~1MB working set per XCD L2.
    const int wg0 = (int)blockIdx.x;
    const int wg  = (wg0 & 7) * 64 + (wg0 >> 3);
    const int bx  = wg & 15;            // j-block 0..15
    const int by  = wg >> 4;            // n-block 0..31

    const int n0  = by * 64;
    const int j0w = bx * 16 + wid * 4;  // this wave's 4 output columns (uniform)

    // Staging: one global_load_lds(16B) moves 1024B = one row-pair.
    const int sub  = lane >> 5;          // row within pair
    const int kl   = (lane & 31) * 4;    // float offset within row
    // Compute-side read base: row = lane; pair p at p*PP, odd row at +BK floats.
    const int xoff = (lane >> 1) * PP + (lane & 1) * BK;

    const float* wrow = w + (size_t)j0w * K_;   // uniform SGPR base for s_load

    float mx[4], mn[4];
#pragma unroll
    for (int j = 0; j < 4; ++j) { mx[j] = -__builtin_inff(); mn[j] = __builtin_inff(); }

#define STAGE(buf, kc)                                                            \
    {                                                                             \
        _Pragma("unroll")                                                         \
        for (int p = 0; p < 8; ++p) {                                             \
            const int pair = wid * 8 + p;                                         \
            __builtin_amdgcn_global_load_lds(                                     \
                (glb_f*)(x + (size_t)(n0 + pair * 2 + sub) * K_ + (kc) + kl),     \
                (lds_f*)(&xs[buf][pair * PP]), 16, 0, 0);                         \
        }                                                                         \
    }

    // Per 16-k group: 4 ds_read_b128 (x, per-lane row) overlap with 4 s_load_dwordx16
    // (w, 4 j-rows x 16 k -> 64 SGPRs); one shared lgkmcnt(0); then 128 VALU ops.
#define CHUNK(buf, kc)                                                            \
    {                                                                             \
        const float* wr = wrow + (kc);                                            \
        _Pragma("unroll")                                                         \
        for (int g = 0; g < BK / 16; ++g) {                                       \
            float4 xq[4];                                                         \
            _Pragma("unroll")                                                     \
            for (int q = 0; q < 4; ++q)                                           \
                xq[q] = *(const float4*)&xs[buf][xoff + g * 16 + q * 4];          \
            f32x16 wv[4];                                                         \
            asm volatile(                                                         \
                "s_load_dwordx16 %0, %4, %5\n\t"                                  \
                "s_load_dwordx16 %1, %4, %6\n\t"                                  \
                "s_load_dwordx16 %2, %4, %7\n\t"                                  \
                "s_load_dwordx16 %3, %4, %8\n\t"                                  \
                "s_waitcnt lgkmcnt(0)"                                            \
                : "=&s"(wv[0]), "=&s"(wv[1]), "=&s"(wv[2]), "=&s"(wv[3])          \
                : "s"(wr), "i"(g * 64), "i"(2048 + g * 64),                       \
                  "i"(4096 + g * 64), "i"(6144 + g * 64));                        \
            _Pragma("unroll")                                                     \
            for (int q = 0; q < 4; ++q) {                                         \
                const float xa[4] = {xq[q].x, xq[q].y, xq[q].z, xq[q].w};         \
                _Pragma("unroll")                                                 \
                for (int j = 0; j < 4; ++j) {                                     \
                    const float p0 = xa[0] * wv[j][g * 0 + q * 4 + 0];            \
                    const float p1 = xa[1] * wv[j][q * 4 + 1];                    \
                    const float p2 = xa[2] * wv[j][q * 4 + 2];                    \
                    const float p3 = xa[3] * wv[j][q * 4 + 3];                    \
                    MAX3(mx[j], p0, p1); MAX3(mx[j], p2, p3);                     \
                    MIN3(mn[j], p0, p1); MIN3(mn[j], p2, p3);                     \
                }                                                                 \
            }                                                                     \
        }                                                                         \
    }

    // Double-buffered over K = 4 chunks of 128; STAGE(c+1) issued before CHUNK(c),
    // __syncthreads drains vmcnt(0) after the compute (s_loads ride lgkmcnt, unaffected).
    STAGE(0, 0);
    __syncthreads();
    STAGE(1, BK);        CHUNK(0, 0);
    __syncthreads();
    STAGE(0, 2 * BK);    CHUNK(1, BK);
    __syncthreads();
    STAGE(1, 3 * BK);    CHUNK(0, 2 * BK);
    __syncthreads();
                         CHUNK(1, 3 * BK);

    const float4 bi = *(const float4*)&bias[j0w];
    float4 o;
    o.x = mx[0] + mn[0] + bi.x;
    o.y = mx[1] + mn[1] + bi.y;
    o.z = mx[2] + mn[2] + bi.z;
    o.w = mx[3] + mn[3] + bi.w;
    *(float4*)&out[(size_t)(n0 + lane) * J_ + j0w] = o;

#undef STAGE
#undef CHUNK
}

extern "C" void kernel_launch(void* const* d_in, const int* in_sizes, int n_in,
                              void* d_out, int out_size, void* d_ws, size_t ws_size,
                              hipStream_t stream) {
    const float* x    = (const float*)d_in[0];
    const float* w    = (const float*)d_in[1];
    const float* bias = (const float*)d_in[2];
    float* out = (float*)d_out;

    dim3 grid(512);   // 32 n-blocks x 16 j-blocks, XCD-swizzled in-kernel
    mam_fused3<<<grid, 256, 0, stream>>>(x, w, bias, out);
}

// Round 3
// 72.097 us; speedup vs baseline: 1.1993x; 1.0736x over previous
//
#include <hip/hip_runtime.h>
#include <math.h>

#define N_ 2048
#define K_ 512
#define J_ 256
#define BK 64             // K floats per step (per k-half), double-buffered
#define NQ 16             // row-quads per chunk (64 rows / 4)
#define PP 260            // floats per quad: 4 rows x 64 + 4 pad (b128 reads at 8-way bank floor)

typedef __attribute__((address_space(3))) float       lds_f;
typedef const __attribute__((address_space(1))) float glb_f;
typedef float f32x16 __attribute__((ext_vector_type(16)));

// 2 muls + 1 max3 + 1 min3 per 2 products = 2.0 VALU ops/product.
#define MAX3(acc, a, b) asm("v_max3_f32 %0, %0, %1, %2" : "+v"(acc) : "v"(a), "v"(b))
#define MIN3(acc, a, b) asm("v_min3_f32 %0, %0, %1, %2" : "+v"(acc) : "v"(a), "v"(b))

// Grid 512 blocks x 512 threads. 8 waves/block = 4 j-subtiles x 2 K-HALVES
// -> 4096 waves total = 4 waves/SIMD (vs 2 before): TLP hides the per-group
// scalar-load latency that the monolithic {s_load;lgkmcnt(0)} block exposes.
// Block tile 64n x 16j; wave: 64 n (row per lane) x 4 j x 256 k (its half).
// x: LDS row-per-lane via global_load_lds quads, double-buffered per half.
// w: scalar pipe (s_load_dwordx16), SGPR operands free on v_mul.
__global__ __launch_bounds__(512) void mam_fused4(
    const float* __restrict__ x, const float* __restrict__ w,
    const float* __restrict__ bias, float* __restrict__ out)
{
    __shared__ __align__(16) float xs[2][2][NQ * PP];   // [half][buf] = 66,560 B -> 2 blocks/CU

    const int t    = threadIdx.x;
    const int lane = t & 63;
    const int wid  = __builtin_amdgcn_readfirstlane(t >> 6);   // 0..7
    const int ks   = wid >> 2;          // k-half: 0 -> k<256, 1 -> k>=256
    const int jw   = wid & 3;           // j-subtile within block

    // XCD-chunked bijective swizzle (512 = 8 * 64).
    const int wg0 = (int)blockIdx.x;
    const int wg  = (wg0 & 7) * 64 + (wg0 >> 3);
    const int bx  = wg & 15;            // j-block 0..15
    const int by  = wg >> 4;            // n-block 0..31

    const int n0  = by * 64;
    const int j0w = bx * 16 + jw * 4;   // wave's 4 output columns (uniform)

    // Staging: one global_load_lds(16B/lane) = 1024B = 4 rows x 64 floats (a quad).
    const int srow = lane >> 4;          // row within quad (0..3)
    const int skl  = (lane & 15) * 4;    // float offset within row
    // Compute-side: row = lane -> quad = lane>>2 at quad*PP, row-in-quad at *BK.
    const int xoff = (lane >> 2) * PP + (lane & 3) * BK;

    const float* wrow = w + (size_t)j0w * K_ + ks * 256;   // uniform s_load base

    float mx[4], mn[4];
#pragma unroll
    for (int j = 0; j < 4; ++j) { mx[j] = -__builtin_inff(); mn[j] = __builtin_inff(); }

    // Each wave stages 4 quads of ITS half's chunk for step s into buf.
#define STAGE(buf, s)                                                             \
    {                                                                             \
        _Pragma("unroll")                                                         \
        for (int p = 0; p < 4; ++p) {                                             \
            const int q = jw * 4 + p;                                             \
            __builtin_amdgcn_global_load_lds(                                     \
                (glb_f*)(x + (size_t)(n0 + q * 4 + srow) * K_                     \
                         + ks * 256 + (s) * BK + skl),                            \
                (lds_f*)(&xs[ks][buf][q * PP]), 16, 0, 0);                        \
        }                                                                         \
    }

    // Per 16-k group: 4 ds_read_b128 (x) + 4 s_load_dwordx16 (w: 4 j-rows x 16 k)
    // + one lgkmcnt(0), then 128 VALU ops.
#define COMPUTE(buf, s)                                                           \
    {                                                                             \
        const float* wr = wrow + (s) * BK;                                        \
        _Pragma("unroll")                                                         \
        for (int g = 0; g < BK / 16; ++g) {                                       \
            float4 xq[4];                                                         \
            _Pragma("unroll")                                                     \
            for (int q = 0; q < 4; ++q)                                           \
                xq[q] = *(const float4*)&xs[ks][buf][xoff + g * 16 + q * 4];      \
            f32x16 wv[4];                                                         \
            asm volatile(                                                         \
                "s_load_dwordx16 %0, %4, %5\n\t"                                  \
                "s_load_dwordx16 %1, %4, %6\n\t"                                  \
                "s_load_dwordx16 %2, %4, %7\n\t"                                  \
                "s_load_dwordx16 %3, %4, %8\n\t"                                  \
                "s_waitcnt lgkmcnt(0)"                                            \
                : "=&s"(wv[0]), "=&s"(wv[1]), "=&s"(wv[2]), "=&s"(wv[3])          \
                : "s"(wr), "i"(g * 64), "i"(2048 + g * 64),                       \
                  "i"(4096 + g * 64), "i"(6144 + g * 64));                        \
            _Pragma("unroll")                                                     \
            for (int q = 0; q < 4; ++q) {                                         \
                const float xa[4] = {xq[q].x, xq[q].y, xq[q].z, xq[q].w};         \
                _Pragma("unroll")                                                 \
                for (int j = 0; j < 4; ++j) {                                     \
                    const float p0 = xa[0] * wv[j][q * 4 + 0];                    \
                    const float p1 = xa[1] * wv[j][q * 4 + 1];                    \
                    const float p2 = xa[2] * wv[j][q * 4 + 2];                    \
                    const float p3 = xa[3] * wv[j][q * 4 + 3];                    \
                    MAX3(mx[j], p0, p1); MAX3(mx[j], p2, p3);                     \
                    MIN3(mn[j], p0, p1); MIN3(mn[j], p2, p3);                     \
                }                                                                 \
            }                                                                     \
        }                                                                         \
    }

    // 4 steps of 64 k per half, double-buffered: STAGE(s+1) issued before
    // COMPUTE(s); __syncthreads drains vmcnt(0).
    STAGE(0, 0);
    __syncthreads();
    STAGE(1, 1);   COMPUTE(0, 0);
    __syncthreads();
    STAGE(0, 2);   COMPUTE(1, 1);
    __syncthreads();
    STAGE(1, 3);   COMPUTE(0, 2);
    __syncthreads();
                   COMPUTE(1, 3);

    // Combine the two k-halves: ks=1 dumps partials to LDS, ks=0 merges.
    __syncthreads();
    float* cb = (float*)&xs[0][0][0];    // 8 KB scratch, xs dead now
    if (ks == 1) {
        float4 a = {mx[0], mx[1], mx[2], mx[3]};
        float4 b = {mn[0], mn[1], mn[2], mn[3]};
        *(float4*)&cb[(jw * 64 + lane) * 8 + 0] = a;
        *(float4*)&cb[(jw * 64 + lane) * 8 + 4] = b;
    }
    __syncthreads();
    if (ks == 0) {
        const float4 a = *(const float4*)&cb[(jw * 64 + lane) * 8 + 0];
        const float4 b = *(const float4*)&cb[(jw * 64 + lane) * 8 + 4];
        const float4 bi = *(const float4*)&bias[j0w];
        float4 o;
        o.x = fmaxf(mx[0], a.x) + fminf(mn[0], b.x) + bi.x;
        o.y = fmaxf(mx[1], a.y) + fminf(mn[1], b.y) + bi.y;
        o.z = fmaxf(mx[2], a.z) + fminf(mn[2], b.z) + bi.z;
        o.w = fmaxf(mx[3], a.w) + fminf(mn[3], b.w) + bi.w;
        *(float4*)&out[(size_t)(n0 + lane) * J_ + j0w] = o;
    }

#undef STAGE
#undef COMPUTE
}

extern "C" void kernel_launch(void* const* d_in, const int* in_sizes, int n_in,
                              void* d_out, int out_size, void* d_ws, size_t ws_size,
                              hipStream_t stream) {
    const float* x    = (const float*)d_in[0];
    const float* w    = (const float*)d_in[1];
    const float* bias = (const float*)d_in[2];
    float* out = (float*)d_out;

    dim3 grid(512);   // 32 n-blocks x 16 j-blocks, XCD-swizzled in-kernel
    mam_fused4<<<grid, 512, 0, stream>>>(x, w, bias, out);
}